// Round 1
// baseline (9649.969 us; speedup 1.0000x reference)
//
#include <hip/hip_runtime.h>
#include <math.h>

// Problem constants
#define NN    20000   // nodes
#define NE    40000   // edges
#define QL    4       // tokens per node
#define HID   512
#define NHEADS 8
#define KVHEADS 2
#define HD    64
#define INTER 2048

// ---------------------------------------------------------------------------
// Workspace layout (float offsets). Total = 269,193,216 floats = ~1.08 GB.
//   region A [0 .. 163,840,000): hn(40.96M) | ehn(81.92M) | ekv(40.96M)
//            later aliased by act (80000*2048 = 163.84M exactly)
//   qkv  [163,840,000 .. 225,280,000)   80000*768
//   o    [225,280,000 .. 266,240,000)   80000*512, later aliased by hn2
//   wp   [266,240,000 .. 266,633,216)   packed [wq;wk;wv] 768*512
//   alpha[266,633,216 .. 267,913,216)   E*H*L
//   amax [267,913,216 .. 268,553,216)   N*H*L (uint-encoded)
//   den  [268,553,216 .. 269,193,216)   N*H*L
// ---------------------------------------------------------------------------
static const size_t OFF_HN    = 0;
static const size_t OFF_EHN   = 40960000;
static const size_t OFF_EKV   = 122880000;
static const size_t OFF_QKV   = 163840000;
static const size_t OFF_O     = 225280000;
static const size_t OFF_WP    = 266240000;
static const size_t OFF_ALPHA = 266633216;
static const size_t OFF_AMAX  = 267913216;
static const size_t OFF_DEN   = 268553216;
static const size_t OFF_ACT   = 0;          // aliases hn/ehn/ekv (all dead by MLP time)
static const size_t OFF_HN2   = 225280000;  // aliases o (dead after wo-GEMM)

// ---------------------------------------------------------------------------
// Pack [wq(512); wk(128); wv(128)] rows into one 768x512 weight. Edge GEMM
// reuses rows 512..767 ([wk;wv]).
// ---------------------------------------------------------------------------
__global__ __launch_bounds__(256) void pack_w_k(
    const float* __restrict__ wq, const float* __restrict__ wk,
    const float* __restrict__ wv, float* __restrict__ wp)
{
    int idx = blockIdx.x * 256 + threadIdx.x;      // < 768*512
    int row = idx >> 9, col = idx & 511;
    float v;
    if (row < 512)      v = wq[idx];
    else if (row < 640) v = wk[(row - 512) * 512 + col];
    else                v = wv[(row - 640) * 512 + col];
    wp[idx] = v;
}

// Zero o and den, fill amax with encoded -inf (ws is poisoned 0xAA each call).
__global__ __launch_bounds__(256) void init_k(
    float* __restrict__ o, float* __restrict__ den, unsigned* __restrict__ amax)
{
    int idx = blockIdx.x * 256 + threadIdx.x;      // grid covers 40,960,000
    o[idx] = 0.0f;
    if (idx < NN * NHEADS * QL) { den[idx] = 0.0f; amax[idx] = 0x007FFFFFu; }
}

// ---------------------------------------------------------------------------
// RMSNorm: one wave (64 lanes) per 512-float row; 8 floats/lane via float4 x2.
// Rows [0,rows1) from x1, rows [rows1,totalRows) from x2 (shared weight).
// ---------------------------------------------------------------------------
__global__ __launch_bounds__(256) void rmsnorm_k(
    const float* __restrict__ x1, int rows1, const float* __restrict__ x2,
    const float* __restrict__ w, float* __restrict__ y, int totalRows)
{
    int wid = (blockIdx.x << 2) + (threadIdx.x >> 6);
    if (wid >= totalRows) return;
    int lane = threadIdx.x & 63;
    const float* src = (wid < rows1) ? (x1 + (size_t)wid * HID)
                                     : (x2 + (size_t)(wid - rows1) * HID);
    float4 v0 = *(const float4*)&src[lane * 8];
    float4 v1 = *(const float4*)&src[lane * 8 + 4];
    float ss = v0.x*v0.x + v0.y*v0.y + v0.z*v0.z + v0.w*v0.w
             + v1.x*v1.x + v1.y*v1.y + v1.z*v1.z + v1.w*v1.w;
    #pragma unroll
    for (int off = 32; off; off >>= 1) ss += __shfl_xor(ss, off);
    float scale = 1.0f / sqrtf(ss * (1.0f / HID) + 1e-6f);
    float4 w0 = *(const float4*)&w[lane * 8];
    float4 w1 = *(const float4*)&w[lane * 8 + 4];
    float* dst = y + (size_t)wid * HID;
    float4 o0 = { v0.x*scale*w0.x, v0.y*scale*w0.y, v0.z*scale*w0.z, v0.w*scale*w0.w };
    float4 o1 = { v1.x*scale*w1.x, v1.y*scale*w1.y, v1.z*scale*w1.z, v1.w*scale*w1.w };
    *(float4*)&dst[lane * 8]     = o0;
    *(float4*)&dst[lane * 8 + 4] = o1;
}

// ---------------------------------------------------------------------------
// Generic fp32 GEMM: C[M,N] = A[M,K] @ W[N,K]^T  (+ epilogue)
//   EPI 0: plain store;  EPI 1: C = acc + R (residual);  EPI 3: C += acc.
// 64x64 tile, BK=16, 256 threads, 4x4 micro-tile/thread. All dims divisible.
// ---------------------------------------------------------------------------
template<int EPI>
__global__ __launch_bounds__(256) void gemm_bt_k(
    const float* __restrict__ A, const float* __restrict__ W,
    const float* __restrict__ R, float* __restrict__ C,
    int M, int N, int K)
{
    __shared__ float As[16][64];
    __shared__ float Bs[16][64];
    const int tid  = threadIdx.x;
    const int row0 = blockIdx.y * 64;
    const int col0 = blockIdx.x * 64;
    const int tx = tid & 15, ty = tid >> 4;
    const int lr = tid >> 2;           // 0..63 (tile row for loads)
    const int lk = (tid & 3) << 2;     // 0,4,8,12 (k offset for loads)
    const float* Ap = A + (size_t)(row0 + lr) * K + lk;
    const float* Wp = W + (size_t)(col0 + lr) * K + lk;
    float acc[4][4] = {};
    for (int k0 = 0; k0 < K; k0 += 16) {
        float4 a4 = *(const float4*)(Ap + k0);
        float4 b4 = *(const float4*)(Wp + k0);
        As[lk+0][lr] = a4.x; As[lk+1][lr] = a4.y; As[lk+2][lr] = a4.z; As[lk+3][lr] = a4.w;
        Bs[lk+0][lr] = b4.x; Bs[lk+1][lr] = b4.y; Bs[lk+2][lr] = b4.z; Bs[lk+3][lr] = b4.w;
        __syncthreads();
        #pragma unroll
        for (int kk = 0; kk < 16; ++kk) {
            float4 av = *(const float4*)&As[kk][ty << 2];
            float4 bv = *(const float4*)&Bs[kk][tx << 2];
            float a[4] = { av.x, av.y, av.z, av.w };
            float b[4] = { bv.x, bv.y, bv.z, bv.w };
            #pragma unroll
            for (int i = 0; i < 4; ++i)
                #pragma unroll
                for (int j = 0; j < 4; ++j)
                    acc[i][j] = fmaf(a[i], b[j], acc[i][j]);
        }
        __syncthreads();
    }
    const int r0 = row0 + (ty << 2);
    const int c0 = col0 + (tx << 2);
    #pragma unroll
    for (int i = 0; i < 4; ++i) {
        float4 v = { acc[i][0], acc[i][1], acc[i][2], acc[i][3] };
        size_t off = (size_t)(r0 + i) * N + c0;
        if (EPI == 1) {
            float4 r = *(const float4*)(R + off);
            v.x += r.x; v.y += r.y; v.z += r.z; v.w += r.w;
        }
        if (EPI == 3) {
            float4 r = *(const float4*)(C + off);
            v.x += r.x; v.y += r.y; v.z += r.z; v.w += r.w;
        }
        *(float4*)(C + off) = v;
    }
}

// ---------------------------------------------------------------------------
// Fused SwiGLU gate/up GEMM: act[M,N] = silu(A@Wg^T) * (A@Wu^T)
// Same tiling; two accumulators; never materializes gate/up (saves ~1.3GB rw).
// ---------------------------------------------------------------------------
__global__ __launch_bounds__(256) void gemm_gu_k(
    const float* __restrict__ A, const float* __restrict__ Wg,
    const float* __restrict__ Wu, float* __restrict__ act,
    int M, int N, int K)
{
    __shared__ float As[16][64];
    __shared__ float Gs[16][64];
    __shared__ float Us[16][64];
    const int tid  = threadIdx.x;
    const int row0 = blockIdx.y * 64;
    const int col0 = blockIdx.x * 64;
    const int tx = tid & 15, ty = tid >> 4;
    const int lr = tid >> 2;
    const int lk = (tid & 3) << 2;
    const float* Ap = A  + (size_t)(row0 + lr) * K + lk;
    const float* Gp = Wg + (size_t)(col0 + lr) * K + lk;
    const float* Up = Wu + (size_t)(col0 + lr) * K + lk;
    float accg[4][4] = {};
    float accu[4][4] = {};
    for (int k0 = 0; k0 < K; k0 += 16) {
        float4 a4 = *(const float4*)(Ap + k0);
        float4 g4 = *(const float4*)(Gp + k0);
        float4 u4 = *(const float4*)(Up + k0);
        As[lk+0][lr] = a4.x; As[lk+1][lr] = a4.y; As[lk+2][lr] = a4.z; As[lk+3][lr] = a4.w;
        Gs[lk+0][lr] = g4.x; Gs[lk+1][lr] = g4.y; Gs[lk+2][lr] = g4.z; Gs[lk+3][lr] = g4.w;
        Us[lk+0][lr] = u4.x; Us[lk+1][lr] = u4.y; Us[lk+2][lr] = u4.z; Us[lk+3][lr] = u4.w;
        __syncthreads();
        #pragma unroll
        for (int kk = 0; kk < 16; ++kk) {
            float4 av = *(const float4*)&As[kk][ty << 2];
            float4 gv = *(const float4*)&Gs[kk][tx << 2];
            float4 uv = *(const float4*)&Us[kk][tx << 2];
            float a[4] = { av.x, av.y, av.z, av.w };
            float g[4] = { gv.x, gv.y, gv.z, gv.w };
            float u[4] = { uv.x, uv.y, uv.z, uv.w };
            #pragma unroll
            for (int i = 0; i < 4; ++i)
                #pragma unroll
                for (int j = 0; j < 4; ++j) {
                    accg[i][j] = fmaf(a[i], g[j], accg[i][j]);
                    accu[i][j] = fmaf(a[i], u[j], accu[i][j]);
                }
        }
        __syncthreads();
    }
    const int r0 = row0 + (ty << 2);
    const int c0 = col0 + (tx << 2);
    #pragma unroll
    for (int i = 0; i < 4; ++i) {
        float4 v;
        float* vp = &v.x;
        #pragma unroll
        for (int j = 0; j < 4; ++j) {
            float g = accg[i][j];
            float s = g / (1.0f + expf(-g));   // silu
            vp[j] = s * accu[i][j];
        }
        *(float4*)(act + (size_t)(r0 + i) * N + c0) = v;
    }
}

// ---------------------------------------------------------------------------
// Per-edge attention scores. One wave per (edge, token): gather q[dst],
// k[src]+ek, apply RoPE, dot over D=64 per head, alpha = dot/8.
// Also atomicMax into amax (order-preserving uint encoding of fp32).
// ---------------------------------------------------------------------------
__global__ __launch_bounds__(256) void att_alpha_k(
    const float* __restrict__ qkv, const float* __restrict__ ekv,
    const int* __restrict__ ei, float* __restrict__ alpha,
    unsigned* __restrict__ amax)
{
    int el = (blockIdx.x << 2) + (threadIdx.x >> 6);
    if (el >= NE * QL) return;
    int lane = threadIdx.x & 63;
    int e = el >> 2, l = el & 3;
    int src = ei[e], dst = ei[NE + e];

    // RoPE: cos/sin for (token l, dim lane); inv_freq = 10000^-( (lane&31)/32 )
    float invf = expf(-(float)(lane & 31) * (9.210340371976184f / 32.0f));
    float ang  = (float)l * invf;
    float c_ = cosf(ang), s_ = sinf(ang);

    const float* kp = qkv + (size_t)(src * QL + l) * 768 + 512;
    const float* ep = ekv + (size_t)(e  * QL + l) * 256;
    float kr[2];
    #pragma unroll
    for (int kv = 0; kv < 2; ++kv) {
        float x = kp[kv * 64 + lane] + ep[kv * 64 + lane];
        float other = __shfl_xor(x, 32);
        float rot = (lane < 32) ? -other : other;   // rotate_half
        kr[kv] = x * c_ + rot * s_;
    }
    const float* qp = qkv + (size_t)(dst * QL + l) * 768;
    #pragma unroll
    for (int h = 0; h < 8; ++h) {
        float x = qp[h * 64 + lane];
        float other = __shfl_xor(x, 32);
        float rot = (lane < 32) ? -other : other;
        float qr = x * c_ + rot * s_;
        float p = qr * kr[h >> 2];
        #pragma unroll
        for (int off = 32; off; off >>= 1) p += __shfl_xor(p, off);
        if (lane == 0) {
            float a = p * 0.125f;                   // / sqrt(64)
            alpha[(size_t)e * 32 + h * 4 + l] = a;
            unsigned u = __float_as_uint(a);
            u = (u & 0x80000000u) ? ~u : (u | 0x80000000u);
            atomicMax(&amax[(size_t)dst * 32 + h * 4 + l], u);
        }
    }
}

// ex = exp(alpha - amax[dst]); den[dst] += ex (segment softmax denominator)
__global__ __launch_bounds__(256) void att_expden_k(
    const int* __restrict__ ei, float* __restrict__ alpha,
    const unsigned* __restrict__ amax, float* __restrict__ den)
{
    int idx = blockIdx.x * 256 + threadIdx.x;    // < NE*32
    int e = idx >> 5, r = idx & 31;              // r = h*4 + l
    int dst = ei[NE + e];
    unsigned u = amax[dst * 32 + r];
    float m = __uint_as_float((u & 0x80000000u) ? (u ^ 0x80000000u) : ~u);
    float ex = expf(alpha[idx] - m);
    alpha[idx] = ex;
    atomicAdd(&den[dst * 32 + r], ex);
}

// o[dst,l,c] += (v[src]+ev) * softmax_weight — thread per (edge, token, col)
__global__ __launch_bounds__(256) void att_scatter_k(
    const float* __restrict__ qkv, const float* __restrict__ ekv,
    const int* __restrict__ ei, const float* __restrict__ alpha,
    const float* __restrict__ den, float* __restrict__ o)
{
    size_t idx = (size_t)blockIdx.x * 256 + threadIdx.x;  // < NE*QL*512
    int c  = (int)(idx & 511);
    int el = (int)(idx >> 9);
    int e = el >> 2, l = el & 3;
    int h = c >> 6, kv = h >> 2, d = c & 63;
    int src = ei[e], dst = ei[NE + e];
    float ex = alpha[(size_t)e * 32 + h * 4 + l];
    float dn = den[(size_t)dst * 32 + h * 4 + l];
    float w = ex / dn;
    float ve = qkv[(size_t)(src * QL + l) * 768 + 640 + kv * 64 + d]
             + ekv[(size_t)(e  * QL + l) * 256 + 128 + kv * 64 + d];
    atomicAdd(&o[(size_t)(dst * QL + l) * 512 + c], ve * w);
}

// ---------------------------------------------------------------------------
extern "C" void kernel_launch(void* const* d_in, const int* in_sizes, int n_in,
                              void* d_out, int out_size, void* d_ws, size_t ws_size,
                              hipStream_t stream)
{
    const float* hidden  = (const float*)d_in[0];
    const float* ehidden = (const float*)d_in[1];
    const int*   ei      = (const int*)  d_in[2];
    const float* ln1     = (const float*)d_in[3];
    const float* ln2     = (const float*)d_in[4];
    const float* wq      = (const float*)d_in[5];
    const float* wk      = (const float*)d_in[6];
    const float* wv      = (const float*)d_in[7];
    const float* wo      = (const float*)d_in[8];
    const float* wg      = (const float*)d_in[9];
    const float* wu      = (const float*)d_in[10];
    const float* wd      = (const float*)d_in[11];
    float* ws  = (float*)d_ws;
    float* out = (float*)d_out;

    float*    hn    = ws + OFF_HN;
    float*    ehn   = ws + OFF_EHN;
    float*    ekv   = ws + OFF_EKV;
    float*    qkv   = ws + OFF_QKV;
    float*    o     = ws + OFF_O;
    float*    wp    = ws + OFF_WP;
    float*    alpha = ws + OFF_ALPHA;
    unsigned* amax  = (unsigned*)(ws + OFF_AMAX);
    float*    den   = ws + OFF_DEN;
    float*    act   = ws + OFF_ACT;    // aliases hn/ehn/ekv (dead by then)
    float*    hn2   = ws + OFF_HN2;    // aliases o (dead by then)

    // 1. pack [wq;wk;wv] -> 768x512
    pack_w_k<<<1536, 256, 0, stream>>>(wq, wk, wv, wp);
    // 2. RMSNorm nodes (80000 rows) + edges (160000 rows), shared ln1 weight
    rmsnorm_k<<<60000, 256, 0, stream>>>(hidden, 80000, ehidden, ln1, hn, 240000);
    // 3. node projections: qkv[80000,768]
    gemm_bt_k<0><<<dim3(12, 1250), 256, 0, stream>>>(hn, wp, nullptr, qkv, 80000, 768, 512);
    // 4. edge projections: ekv[160000,256] using packed rows 512..767 ([wk;wv])
    gemm_bt_k<0><<<dim3(4, 2500), 256, 0, stream>>>(ehn, wp + 512 * 512, nullptr, ekv, 160000, 256, 512);
    // 5. zero o/den, amax = enc(-inf)
    init_k<<<160000, 256, 0, stream>>>(o, den, amax);
    // 6. per-edge scores + segment max
    att_alpha_k<<<40000, 256, 0, stream>>>(qkv, ekv, ei, alpha, amax);
    // 7. exp + segment sum
    att_expden_k<<<5000, 256, 0, stream>>>(ei, alpha, amax, den);
    // 8. weighted value scatter-add into o
    att_scatter_k<<<320000, 256, 0, stream>>>(qkv, ekv, ei, alpha, den, o);
    // 9. h = hidden + o @ wo^T  -> d_out
    gemm_bt_k<1><<<dim3(8, 1250), 256, 0, stream>>>(o, wo, hidden, out, 80000, 512, 512);
    // 10. hn2 = rmsnorm(h, ln2)
    rmsnorm_k<<<20000, 256, 0, stream>>>(out, 80000, out, ln2, hn2, 80000);
    // 11. act = silu(hn2@wg^T) * (hn2@wu^T)
    gemm_gu_k<<<dim3(32, 1250), 256, 0, stream>>>(hn2, wg, wu, act, 80000, 2048, 512);
    // 12. out = h + act @ wd^T
    gemm_bt_k<3><<<dim3(8, 1250), 256, 0, stream>>>(act, wd, nullptr, out, 80000, 512, 2048);
}

// Round 2
// 2308.930 us; speedup vs baseline: 4.1794x; 4.1794x over previous
//
#include <hip/hip_runtime.h>
#include <math.h>

// Problem constants
#define NN    20000
#define NE    40000
#define QL    4
#define HID   512
#define INTER 2048

typedef _Float16 half8 __attribute__((ext_vector_type(8)));
typedef float floatx4 __attribute__((ext_vector_type(4)));

// async global->LDS, 16B per lane. LDS dest = wave-uniform base + lane*16.
#define GLOADLDS16(g, l) __builtin_amdgcn_global_load_lds( \
    (const __attribute__((address_space(1))) void*)(const void*)(g), \
    (__attribute__((address_space(3))) void*)(void*)(l), 16, 0, 0)

// ---------------------------------------------------------------------------
// Workspace layout (BYTE offsets). Total ~919 MB (round-1 used 1077 MB: fits).
//   [0, 245,760,000)           hn16 (80000x512 fp16) | ehn16 (160000x512 fp16)
//                              later: o16 (81.92MB) then act16 (327.68MB,
//                              spills 81.92MB into dead qkv region)
//   [245,760,000, 491,520,000) qkv fp32 80000x768
//   [491,520,000, 655,360,000) ekv fp32 160000x256
//   [655,360,000, 819,200,000) o   fp32 80000x512
//   [819,200,000, 901,120,000) hn2_16 fp16 80000x512
//   [901,120,000, ...)         alpha | amax | den | fp16 weights
// ---------------------------------------------------------------------------

// ---- pack + convert all weights to fp16 ------------------------------------
// wp = [wq;wk;wv] 768x512; then wo16, wg16, wu16, wd16 straight converts.
__global__ __launch_bounds__(256) void pack_w16_k(
    const float* __restrict__ wq, const float* __restrict__ wk,
    const float* __restrict__ wv, const float* __restrict__ wo,
    const float* __restrict__ wg, const float* __restrict__ wu,
    const float* __restrict__ wd, _Float16* __restrict__ wp,
    _Float16* __restrict__ wo16, _Float16* __restrict__ wg16,
    _Float16* __restrict__ wu16, _Float16* __restrict__ wd16)
{
    int idx = blockIdx.x * 256 + threadIdx.x;
    if (idx < 393216) {
        int row = idx >> 9, col = idx & 511;
        float v;
        if (row < 512)      v = wq[idx];
        else if (row < 640) v = wk[(row - 512) * 512 + col];
        else                v = wv[(row - 640) * 512 + col];
        wp[idx] = (_Float16)v;
    } else if (idx < 655360) {
        wo16[idx - 393216] = (_Float16)wo[idx - 393216];
    } else if (idx < 1703936) {
        wg16[idx - 655360] = (_Float16)wg[idx - 655360];
    } else if (idx < 2752512) {
        wu16[idx - 1703936] = (_Float16)wu[idx - 1703936];
    } else if (idx < 3801088) {
        wd16[idx - 2752512] = (_Float16)wd[idx - 2752512];
    }
}

// Zero o and den, fill amax with encoded -inf.
__global__ __launch_bounds__(256) void init_k(
    float* __restrict__ o, float* __restrict__ den, unsigned* __restrict__ amax)
{
    int idx = blockIdx.x * 256 + threadIdx.x;      // covers 40,960,000
    o[idx] = 0.0f;
    if (idx < NN * 32) { den[idx] = 0.0f; amax[idx] = 0x007FFFFFu; }
}

// ---- RMSNorm fp32 in -> fp16 out (one wave per 512-row) --------------------
__global__ __launch_bounds__(256) void rmsnorm16_k(
    const float* __restrict__ x1, int rows1, const float* __restrict__ x2,
    const float* __restrict__ w, _Float16* __restrict__ y, int totalRows)
{
    int wid = (blockIdx.x << 2) + (threadIdx.x >> 6);
    if (wid >= totalRows) return;
    int lane = threadIdx.x & 63;
    const float* src = (wid < rows1) ? (x1 + (size_t)wid * HID)
                                     : (x2 + (size_t)(wid - rows1) * HID);
    float4 v0 = *(const float4*)&src[lane * 8];
    float4 v1 = *(const float4*)&src[lane * 8 + 4];
    float ss = v0.x*v0.x + v0.y*v0.y + v0.z*v0.z + v0.w*v0.w
             + v1.x*v1.x + v1.y*v1.y + v1.z*v1.z + v1.w*v1.w;
    #pragma unroll
    for (int off = 32; off; off >>= 1) ss += __shfl_xor(ss, off);
    float scale = 1.0f / sqrtf(ss * (1.0f / HID) + 1e-6f);
    float4 w0 = *(const float4*)&w[lane * 8];
    float4 w1 = *(const float4*)&w[lane * 8 + 4];
    half8 o;
    o[0] = (_Float16)(v0.x * scale * w0.x);
    o[1] = (_Float16)(v0.y * scale * w0.y);
    o[2] = (_Float16)(v0.z * scale * w0.z);
    o[3] = (_Float16)(v0.w * scale * w0.w);
    o[4] = (_Float16)(v1.x * scale * w1.x);
    o[5] = (_Float16)(v1.y * scale * w1.y);
    o[6] = (_Float16)(v1.z * scale * w1.z);
    o[7] = (_Float16)(v1.w * scale * w1.w);
    *(half8*)&y[(size_t)wid * HID + lane * 8] = o;
}

// fp32 -> fp16 bulk convert (8 elems/thread)
__global__ __launch_bounds__(256) void cvt16_k(
    const float* __restrict__ x, _Float16* __restrict__ y)
{
    size_t i = ((size_t)blockIdx.x * 256 + threadIdx.x) * 8;
    float4 a = *(const float4*)&x[i];
    float4 b = *(const float4*)&x[i + 4];
    half8 o;
    o[0] = (_Float16)a.x; o[1] = (_Float16)a.y; o[2] = (_Float16)a.z; o[3] = (_Float16)a.w;
    o[4] = (_Float16)b.x; o[5] = (_Float16)b.y; o[6] = (_Float16)b.z; o[7] = (_Float16)b.w;
    *(half8*)&y[i] = o;
}

// ---------------------------------------------------------------------------
// fp16 MFMA GEMM: C[M,N] = A[M,K] @ W[N,K]^T (+ epilogue), fp32 out.
// 128x128 tile, BK=64, 4 waves (2x2, 64x64 each), mfma_f32_16x16x32_f16.
// Staging: global_load_lds 16B with pre-swizzled SOURCE slot (slot^row&7);
// ds_read_b128 applies the same XOR -> 2-way banked (free).
//   EPI 0: C = acc;  EPI 1: C = acc + R;  EPI 3: C += acc.
// ---------------------------------------------------------------------------
template<int EPI>
__global__ __launch_bounds__(256) void gemm16_k(
    const _Float16* __restrict__ A, const _Float16* __restrict__ W,
    const float* __restrict__ R, float* __restrict__ C,
    int M, int N, int K)
{
    __shared__ alignas(128) _Float16 As[128 * 64];
    __shared__ alignas(128) _Float16 Bs[128 * 64];
    const int tid  = threadIdx.x;
    const int lane = tid & 63;
    const int wid  = tid >> 6;
    const int wm = wid >> 1, wn = wid & 1;
    const int fr = lane & 15, fk = lane >> 4;
    const int row0 = blockIdx.y * 128;
    const int col0 = blockIdx.x * 128;
    const int srow  = tid >> 3;     // staging row (i adds 32)
    const int sslot = tid & 7;      // staging 16B slot within row
    const int ldst  = (tid >> 6) << 10;  // wave-uniform LDS byte base

    floatx4 acc[4][4];
    #pragma unroll
    for (int i = 0; i < 4; ++i)
        #pragma unroll
        for (int j = 0; j < 4; ++j)
            acc[i][j] = floatx4{0.f, 0.f, 0.f, 0.f};

    for (int k0 = 0; k0 < K; k0 += 64) {
        #pragma unroll
        for (int i = 0; i < 4; ++i) {
            int row = srow + i * 32;
            int gs  = ((sslot ^ (row & 7)) << 3);
            GLOADLDS16(A + (size_t)(row0 + row) * K + k0 + gs, (char*)As + i * 4096 + ldst);
            GLOADLDS16(W + (size_t)(col0 + row) * K + k0 + gs, (char*)Bs + i * 4096 + ldst);
        }
        __syncthreads();   // drains vmcnt(0)
        #pragma unroll
        for (int kk = 0; kk < 2; ++kk) {
            half8 af[4], bf[4];
            #pragma unroll
            for (int mt = 0; mt < 4; ++mt) {
                int r = wm * 64 + mt * 16 + fr;
                af[mt] = *(const half8*)((const char*)As + r * 128 + ((((kk << 2) + fk) ^ (r & 7)) << 4));
            }
            #pragma unroll
            for (int nt = 0; nt < 4; ++nt) {
                int r = wn * 64 + nt * 16 + fr;
                bf[nt] = *(const half8*)((const char*)Bs + r * 128 + ((((kk << 2) + fk) ^ (r & 7)) << 4));
            }
            #pragma unroll
            for (int mt = 0; mt < 4; ++mt)
                #pragma unroll
                for (int nt = 0; nt < 4; ++nt)
                    acc[mt][nt] = __builtin_amdgcn_mfma_f32_16x16x32_f16(af[mt], bf[nt], acc[mt][nt], 0, 0, 0);
        }
        __syncthreads();
    }
    // C/D layout: col = lane&15, row = (lane>>4)*4 + reg  [m89-verified]
    #pragma unroll
    for (int mt = 0; mt < 4; ++mt)
        #pragma unroll
        for (int nt = 0; nt < 4; ++nt)
            #pragma unroll
            for (int j = 0; j < 4; ++j) {
                int r = row0 + wm * 64 + mt * 16 + fk * 4 + j;
                int c = col0 + wn * 64 + nt * 16 + fr;
                size_t off = (size_t)r * N + c;
                float v = acc[mt][nt][j];
                if (EPI == 1) v += R[off];
                if (EPI == 3) v += C[off];
                C[off] = v;
            }
}

// ---------------------------------------------------------------------------
// Fused SwiGLU gate/up fp16 GEMM: act[M,N] = silu(A@Wg^T) * (A@Wu^T), fp16 out.
// 128x64 tile (M x Ncols), 4 waves 2x2 (64x32 each), dual accumulators.
// ---------------------------------------------------------------------------
__global__ __launch_bounds__(256) void gemm_gu16_k(
    const _Float16* __restrict__ A, const _Float16* __restrict__ Wg,
    const _Float16* __restrict__ Wu, _Float16* __restrict__ act,
    int M, int N, int K)
{
    __shared__ alignas(128) _Float16 As[128 * 64];
    __shared__ alignas(128) _Float16 Gs[64 * 64];
    __shared__ alignas(128) _Float16 Us[64 * 64];
    const int tid  = threadIdx.x;
    const int lane = tid & 63;
    const int wid  = tid >> 6;
    const int wm = wid >> 1, wn = wid & 1;
    const int fr = lane & 15, fk = lane >> 4;
    const int row0 = blockIdx.y * 128;
    const int col0 = blockIdx.x * 64;
    const int srow  = tid >> 3;
    const int sslot = tid & 7;
    const int ldst  = (tid >> 6) << 10;

    floatx4 ag[4][2], au[4][2];
    #pragma unroll
    for (int i = 0; i < 4; ++i)
        #pragma unroll
        for (int j = 0; j < 2; ++j) {
            ag[i][j] = floatx4{0.f, 0.f, 0.f, 0.f};
            au[i][j] = floatx4{0.f, 0.f, 0.f, 0.f};
        }

    for (int k0 = 0; k0 < K; k0 += 64) {
        #pragma unroll
        for (int i = 0; i < 4; ++i) {
            int row = srow + i * 32;
            int gs  = ((sslot ^ (row & 7)) << 3);
            GLOADLDS16(A + (size_t)(row0 + row) * K + k0 + gs, (char*)As + i * 4096 + ldst);
        }
        #pragma unroll
        for (int i = 0; i < 2; ++i) {
            int row = srow + i * 32;
            int gs  = ((sslot ^ (row & 7)) << 3);
            GLOADLDS16(Wg + (size_t)(col0 + row) * K + k0 + gs, (char*)Gs + i * 4096 + ldst);
            GLOADLDS16(Wu + (size_t)(col0 + row) * K + k0 + gs, (char*)Us + i * 4096 + ldst);
        }
        __syncthreads();
        #pragma unroll
        for (int kk = 0; kk < 2; ++kk) {
            half8 af[4], gf[2], uf[2];
            #pragma unroll
            for (int mt = 0; mt < 4; ++mt) {
                int r = wm * 64 + mt * 16 + fr;
                af[mt] = *(const half8*)((const char*)As + r * 128 + ((((kk << 2) + fk) ^ (r & 7)) << 4));
            }
            #pragma unroll
            for (int nt = 0; nt < 2; ++nt) {
                int r = wn * 32 + nt * 16 + fr;
                int boff = r * 128 + ((((kk << 2) + fk) ^ (r & 7)) << 4);
                gf[nt] = *(const half8*)((const char*)Gs + boff);
                uf[nt] = *(const half8*)((const char*)Us + boff);
            }
            #pragma unroll
            for (int mt = 0; mt < 4; ++mt)
                #pragma unroll
                for (int nt = 0; nt < 2; ++nt) {
                    ag[mt][nt] = __builtin_amdgcn_mfma_f32_16x16x32_f16(af[mt], gf[nt], ag[mt][nt], 0, 0, 0);
                    au[mt][nt] = __builtin_amdgcn_mfma_f32_16x16x32_f16(af[mt], uf[nt], au[mt][nt], 0, 0, 0);
                }
        }
        __syncthreads();
    }
    #pragma unroll
    for (int mt = 0; mt < 4; ++mt)
        #pragma unroll
        for (int nt = 0; nt < 2; ++nt)
            #pragma unroll
            for (int j = 0; j < 4; ++j) {
                int r = row0 + wm * 64 + mt * 16 + fk * 4 + j;
                int c = col0 + wn * 32 + nt * 16 + fr;
                float g = ag[mt][nt][j];
                float u = au[mt][nt][j];
                float s = g / (1.0f + expf(-g));
                act[(size_t)r * N + c] = (_Float16)(s * u);
            }
}

// ---------------------------------------------------------------------------
// Attention (unchanged from round 1, fp32): scores+segmax, exp+den, scatter.
// ---------------------------------------------------------------------------
__global__ __launch_bounds__(256) void att_alpha_k(
    const float* __restrict__ qkv, const float* __restrict__ ekv,
    const int* __restrict__ ei, float* __restrict__ alpha,
    unsigned* __restrict__ amax)
{
    int el = (blockIdx.x << 2) + (threadIdx.x >> 6);
    if (el >= NE * QL) return;
    int lane = threadIdx.x & 63;
    int e = el >> 2, l = el & 3;
    int src = ei[e], dst = ei[NE + e];

    float invf = expf(-(float)(lane & 31) * (9.210340371976184f / 32.0f));
    float ang  = (float)l * invf;
    float c_ = cosf(ang), s_ = sinf(ang);

    const float* kp = qkv + (size_t)(src * QL + l) * 768 + 512;
    const float* ep = ekv + (size_t)(e  * QL + l) * 256;
    float kr[2];
    #pragma unroll
    for (int kv = 0; kv < 2; ++kv) {
        float x = kp[kv * 64 + lane] + ep[kv * 64 + lane];
        float other = __shfl_xor(x, 32);
        float rot = (lane < 32) ? -other : other;
        kr[kv] = x * c_ + rot * s_;
    }
    const float* qp = qkv + (size_t)(dst * QL + l) * 768;
    #pragma unroll
    for (int h = 0; h < 8; ++h) {
        float x = qp[h * 64 + lane];
        float other = __shfl_xor(x, 32);
        float rot = (lane < 32) ? -other : other;
        float qr = x * c_ + rot * s_;
        float p = qr * kr[h >> 2];
        #pragma unroll
        for (int off = 32; off; off >>= 1) p += __shfl_xor(p, off);
        if (lane == 0) {
            float a = p * 0.125f;
            alpha[(size_t)e * 32 + h * 4 + l] = a;
            unsigned u = __float_as_uint(a);
            u = (u & 0x80000000u) ? ~u : (u | 0x80000000u);
            atomicMax(&amax[(size_t)dst * 32 + h * 4 + l], u);
        }
    }
}

__global__ __launch_bounds__(256) void att_expden_k(
    const int* __restrict__ ei, float* __restrict__ alpha,
    const unsigned* __restrict__ amax, float* __restrict__ den)
{
    int idx = blockIdx.x * 256 + threadIdx.x;    // < NE*32
    int e = idx >> 5, r = idx & 31;
    int dst = ei[NE + e];
    unsigned u = amax[dst * 32 + r];
    float m = __uint_as_float((u & 0x80000000u) ? (u ^ 0x80000000u) : ~u);
    float ex = expf(alpha[idx] - m);
    alpha[idx] = ex;
    atomicAdd(&den[dst * 32 + r], ex);
}

__global__ __launch_bounds__(256) void att_scatter_k(
    const float* __restrict__ qkv, const float* __restrict__ ekv,
    const int* __restrict__ ei, const float* __restrict__ alpha,
    const float* __restrict__ den, float* __restrict__ o)
{
    size_t idx = (size_t)blockIdx.x * 256 + threadIdx.x;  // < NE*QL*512
    int c  = (int)(idx & 511);
    int el = (int)(idx >> 9);
    int e = el >> 2, l = el & 3;
    int h = c >> 6, kv = h >> 2, d = c & 63;
    int src = ei[e], dst = ei[NE + e];
    float ex = alpha[(size_t)e * 32 + h * 4 + l];
    float dn = den[(size_t)dst * 32 + h * 4 + l];
    float w = ex / dn;
    float ve = qkv[(size_t)(src * QL + l) * 768 + 640 + kv * 64 + d]
             + ekv[(size_t)(e  * QL + l) * 256 + 128 + kv * 64 + d];
    atomicAdd(&o[(size_t)(dst * QL + l) * 512 + c], ve * w);
}

// ---------------------------------------------------------------------------
extern "C" void kernel_launch(void* const* d_in, const int* in_sizes, int n_in,
                              void* d_out, int out_size, void* d_ws, size_t ws_size,
                              hipStream_t stream)
{
    const float* hidden  = (const float*)d_in[0];
    const float* ehidden = (const float*)d_in[1];
    const int*   ei      = (const int*)  d_in[2];
    const float* ln1     = (const float*)d_in[3];
    const float* ln2     = (const float*)d_in[4];
    const float* wq      = (const float*)d_in[5];
    const float* wk      = (const float*)d_in[6];
    const float* wv      = (const float*)d_in[7];
    const float* wo      = (const float*)d_in[8];
    const float* wg      = (const float*)d_in[9];
    const float* wu      = (const float*)d_in[10];
    const float* wd      = (const float*)d_in[11];
    char* wsb  = (char*)d_ws;
    float* out = (float*)d_out;

    _Float16* hn16  = (_Float16*)(wsb + 0);             // nodes, then edges contiguous
    float*    qkv   = (float*)(wsb + 245760000);
    float*    ekv   = (float*)(wsb + 491520000);
    float*    o     = (float*)(wsb + 655360000);
    _Float16* hn2   = (_Float16*)(wsb + 819200000);
    float*    alpha = (float*)(wsb + 901120000);
    unsigned* amax  = (unsigned*)(wsb + 906240000);
    float*    den   = (float*)(wsb + 908800000);
    _Float16* wp    = (_Float16*)(wsb + 911360000);     // 768x512
    _Float16* wo16  = wp   + 393216;
    _Float16* wg16  = wo16 + 262144;
    _Float16* wu16  = wg16 + 1048576;
    _Float16* wd16  = wu16 + 1048576;
    _Float16* o16   = (_Float16*)(wsb + 0);             // aliases hn16 (dead)
    _Float16* act16 = (_Float16*)(wsb + 0);             // aliases hn16..qkv (dead)

    // 1. weights -> fp16 (packed qkv)
    pack_w16_k<<<14848, 256, 0, stream>>>(wq, wk, wv, wo, wg, wu, wd,
                                          wp, wo16, wg16, wu16, wd16);
    // 2. RMSNorm nodes+edges -> fp16
    rmsnorm16_k<<<60000, 256, 0, stream>>>(hidden, 80000, ehidden, ln1, hn16, 240000);
    // 3. qkv[80000,768] = hn16 @ wp^T
    gemm16_k<0><<<dim3(6, 625), 256, 0, stream>>>(hn16, wp, nullptr, qkv, 80000, 768, 512);
    // 4. ekv[160000,256] = ehn16 @ [wk;wv]^T
    gemm16_k<0><<<dim3(2, 1250), 256, 0, stream>>>(hn16 + (size_t)80000 * 512, wp + 512 * 512,
                                                   nullptr, ekv, 160000, 256, 512);
    // 5. zero o/den, amax = -inf
    init_k<<<160000, 256, 0, stream>>>(o, den, amax);
    // 6-8. attention
    att_alpha_k<<<40000, 256, 0, stream>>>(qkv, ekv, ei, alpha, amax);
    att_expden_k<<<5000, 256, 0, stream>>>(ei, alpha, amax, den);
    att_scatter_k<<<320000, 256, 0, stream>>>(qkv, ekv, ei, alpha, den, o);
    // 9. o -> fp16
    cvt16_k<<<20000, 256, 0, stream>>>(o, o16);
    // 10. out = hidden + o16 @ wo^T
    gemm16_k<1><<<dim3(4, 625), 256, 0, stream>>>(o16, wo16, hidden, out, 80000, 512, 512);
    // 11. hn2 = rmsnorm(out, ln2) -> fp16
    rmsnorm16_k<<<20000, 256, 0, stream>>>(out, 80000, out, ln2, hn2, 80000);
    // 12. act16 = silu(hn2@wg^T) * (hn2@wu^T)
    gemm_gu16_k<<<dim3(32, 625), 256, 0, stream>>>(hn2, wg16, wu16, act16, 80000, 2048, 512);
    // 13. out += act16 @ wd^T
    gemm16_k<3><<<dim3(4, 625), 256, 0, stream>>>(act16, wd16, nullptr, out, 80000, 512, 2048);
}